// Round 3
// baseline (1664.001 us; speedup 1.0000x reference)
//
#include <hip/hip_runtime.h>

#define BB 2
#define NN 512
#define JJ 32
#define DD 256
#define HH 8
#define MM 5
#define MD 1280

// workspace layout (float offsets)
#define OFF_WQ   0          // 256x256 transposed
#define OFF_WK   65536
#define OFF_GS1  131072
#define OFF_GV1  196608
#define OFF_WRE  262144
#define OFF_GS2  327680     // 256x1280 transposed
#define OFF_GV2  655360
#define OFF_WRS  983040
#define OFF_Q    1310720    // B*N*D
#define OFF_K    1572864
#define OFF_X    1835008    // B*N*MD
#define OFF_V    3145728
#define OFF_MSK  4456448    // normalized mask, 32768 bytes (8192 floats)
// total 4464640 floats = 17.9 MB

__device__ __forceinline__ float silu_f(float x){ return x / (1.0f + expf(-x)); }

// ---------------- mask normalization: detect int32 vs byte layout ----------------
// Harness passes integer-kind inputs as int32; jax bool may arrive as int32 or
// as raw bytes. Detect at runtime: int32 layout => all words in {0,1}. Byte
// layout => first 8192 words (=32768 bytes, in-bounds either way) contain a
// nonzero byte above byte0 with probability 1 - 8^-8192.
__global__ void mask_norm_kernel(const unsigned int* __restrict__ raw,
                                 unsigned char* __restrict__ out) {
    __shared__ int flag_s;
    const int tid = threadIdx.x;          // single block, 256 threads
    if (tid == 0) flag_s = 0;
    __syncthreads();
    int bad = 0;
    for (int i = tid; i < 8192; i += 256) bad |= (raw[i] > 1u) ? 1 : 0;
    if (bad) atomicOr(&flag_s, 1);
    __syncthreads();
    if (flag_s) {   // byte layout
        const unsigned char* rb = (const unsigned char*)raw;
        for (int i = tid; i < BB*NN*JJ; i += 256) out[i] = rb[i] ? 1 : 0;
    } else {        // int32 layout
        for (int i = tid; i < BB*NN*JJ; i += 256) out[i] = raw[i] ? 1 : 0;
    }
}

// ---------------- transpose all weight matrices into ws ----------------
__global__ void transpose_kernel(const float* __restrict__ Wq, const float* __restrict__ Wk,
                                 const float* __restrict__ gs1, const float* __restrict__ gv1,
                                 const float* __restrict__ Wre, const float* __restrict__ gs2,
                                 const float* __restrict__ gv2, const float* __restrict__ Wrs,
                                 float* __restrict__ ws) {
    int idx = blockIdx.x * 256 + threadIdx.x;   // grid covers exactly 1310720
    if (idx < 327680) {
        int m = idx >> 16;            // which square matrix
        int local = idx & 65535;
        int e = local >> 8, d0 = local & 255;
        const float* src = (m==0)?Wq:(m==1)?Wk:(m==2)?gs1:(m==3)?gv1:Wre;
        ws[idx] = src[d0*256 + e];    // WT[e][d] = W[d][e]
    } else {
        int t = idx - 327680;
        int m = t / 327680;           // 0=gs2 1=gv2 2=Wrs
        int local = t - m*327680;
        int e = local / 1280;
        int f = local - e*1280;
        const float* src = (m==0)?gs2:(m==1)?gv2:Wrs;
        ws[idx] = src[f*256 + e];     // WT[e][f] = W[f][e]
    }
}

// ---------------- node kernel: LN + q,k + gated MLPs x,v ----------------
__global__ __launch_bounds__(256) void node_kernel(const float* __restrict__ h,
                                                   const float* __restrict__ ln_w,
                                                   const float* __restrict__ ln_b,
                                                   float* __restrict__ ws) {
    __shared__ float hs[8][256];
    __shared__ float s1s[8][256];
    __shared__ float v1s[8][256];
    __shared__ float mu_s[8], rstd_s[8];
    const int tid = threadIdx.x;
    const int row0 = blockIdx.x * 8;

    #pragma unroll
    for (int r = 0; r < 8; r++) hs[r][tid] = h[(size_t)(row0 + r)*256 + tid];
    __syncthreads();

    {
        int g = tid >> 5, l = tid & 31;
        float s = 0.f;
        #pragma unroll
        for (int k = 0; k < 8; k++) s += hs[g][l + 32*k];
        #pragma unroll
        for (int off = 16; off > 0; off >>= 1) s += __shfl_xor(s, off, 32);
        float mu = s * (1.0f/256.0f);
        float v = 0.f;
        #pragma unroll
        for (int k = 0; k < 8; k++) { float d0 = hs[g][l + 32*k] - mu; v += d0*d0; }
        #pragma unroll
        for (int off = 16; off > 0; off >>= 1) v += __shfl_xor(v, off, 32);
        if (l == 0) { mu_s[g] = mu; rstd_s[g] = rsqrtf(v*(1.0f/256.0f) + 1e-5f); }
    }
    __syncthreads();
    {
        float w = ln_w[tid], bb = ln_b[tid];
        #pragma unroll
        for (int r = 0; r < 8; r++) hs[r][tid] = (hs[r][tid] - mu_s[r]) * rstd_s[r] * w + bb;
    }
    __syncthreads();

    {
        float aq[8], ak[8], a1[8], a2[8];
        #pragma unroll
        for (int r = 0; r < 8; r++) { aq[r]=0.f; ak[r]=0.f; a1[r]=0.f; a2[r]=0.f; }
        const float* WqT  = ws + OFF_WQ;
        const float* WkT  = ws + OFF_WK;
        const float* G1T  = ws + OFF_GS1;
        const float* Gv1T = ws + OFF_GV1;
        for (int e = 0; e < 256; e++) {
            float wq = WqT[e*256 + tid];
            float wk = WkT[e*256 + tid];
            float w1 = G1T[e*256 + tid];
            float w2 = Gv1T[e*256 + tid];
            #pragma unroll
            for (int r = 0; r < 8; r++) {
                float hv = hs[r][e];
                aq[r] += hv*wq; ak[r] += hv*wk; a1[r] += hv*w1; a2[r] += hv*w2;
            }
        }
        #pragma unroll
        for (int r = 0; r < 8; r++) {
            ws[OFF_Q + (size_t)(row0 + r)*256 + tid] = aq[r];
            ws[OFF_K + (size_t)(row0 + r)*256 + tid] = ak[r];
            s1s[r][tid] = silu_f(a1[r]);
            v1s[r][tid] = silu_f(a2[r]);
        }
    }
    __syncthreads();

    {
        float ax[8][5], av[8][5];
        #pragma unroll
        for (int r = 0; r < 8; r++)
            #pragma unroll
            for (int m = 0; m < 5; m++) { ax[r][m]=0.f; av[r][m]=0.f; }
        const float* G2T  = ws + OFF_GS2;
        const float* Gv2T = ws + OFF_GV2;
        for (int e = 0; e < 256; e++) {
            float wx[5], wv[5];
            #pragma unroll
            for (int m = 0; m < 5; m++) {
                wx[m] = G2T [e*1280 + m*256 + tid];
                wv[m] = Gv2T[e*1280 + m*256 + tid];
            }
            #pragma unroll
            for (int r = 0; r < 8; r++) {
                float s1v = s1s[r][e], v1v = v1s[r][e];
                #pragma unroll
                for (int m = 0; m < 5; m++) { ax[r][m] += s1v*wx[m]; av[r][m] += v1v*wv[m]; }
            }
        }
        #pragma unroll
        for (int r = 0; r < 8; r++)
            #pragma unroll
            for (int m = 0; m < 5; m++) {
                ws[OFF_X + (size_t)(row0 + r)*1280 + m*256 + tid] = ax[r][m];
                ws[OFF_V + (size_t)(row0 + r)*1280 + m*256 + tid] = av[r][m];
            }
    }
}

// ---------------- edge kernel: one block per (b,i) row ----------------
__global__ __launch_bounds__(256) void edge_kernel(const float* __restrict__ t_ij,
                                                   const float* __restrict__ r_ij,
                                                   const int* __restrict__ nbr,
                                                   const float* __restrict__ r1,
                                                   const float* __restrict__ r2,
                                                   const float* __restrict__ X1,
                                                   const float* __restrict__ X2,
                                                   const float* __restrict__ ws,
                                                   float* __restrict__ out) {
    __shared__ float t_s[JJ][DD];     // 32 KB
    __shared__ float q_s[DD];
    __shared__ float attn_s[JJ][HH];
    __shared__ float cut_s[JJ];
    __shared__ float r1_s[JJ][3];
    __shared__ float r2_s[JJ][5];
    __shared__ int   nbr_s[JJ];
    __shared__ int   msk_s[JJ];
    __shared__ float norm_s;

    const int tid = threadIdx.x;
    const int bi  = blockIdx.x;        // b*N + i
    const int b   = bi >> 9;           // N = 512

    const unsigned char* mask = (const unsigned char*)(ws + OFF_MSK);

    if (tid < JJ) {
        int j = tid;
        int eidx = bi*JJ + j;
        nbr_s[j] = nbr[eidx];
        msk_s[j] = mask[eidx] ? 1 : 0;
        float r = r_ij[eidx];
        cut_s[j] = (r < 5.0f) ? 0.5f*(cosf(r * 0.62831853071795864f) + 1.0f) : 0.0f;
        #pragma unroll
        for (int c = 0; c < 3; c++) r1_s[j][c] = r1[eidx*3 + c];
        #pragma unroll
        for (int c = 0; c < 5; c++) r2_s[j][c] = r2[eidx*5 + c];
    }
    q_s[tid] = ws[OFF_Q + (size_t)bi*256 + tid];
    for (int j = 0; j < JJ; j++)
        t_s[j][tid] = t_ij[((size_t)bi*JJ + j)*256 + tid];
    __syncthreads();
    if (tid == 0) {
        int n = 0;
        for (int j = 0; j < JJ; j++) n += msk_s[j];
        norm_s = sqrtf((float)n) * (1.0f/16.0f);   // sqrt(n)/sqrt(256)
    }

    // --- phase A: t_attn = silu(t @ W_re^T), then per-head logits ---
    float ta[JJ];
    #pragma unroll
    for (int j = 0; j < JJ; j++) ta[j] = 0.f;
    {
        const float* WreT = ws + OFF_WRE;
        for (int e = 0; e < 256; e++) {
            float w = WreT[e*256 + tid];
            #pragma unroll
            for (int j = 0; j < JJ; j++) ta[j] += t_s[j][e] * w;
        }
    }
    {
        float qv = q_s[tid];
        #pragma unroll
        for (int j = 0; j < JJ; j++) {
            float tav = silu_f(ta[j]);
            float kv = ws[OFF_K + (size_t)(b*NN + nbr_s[j])*256 + tid];
            float p = qv * kv * tav;
            #pragma unroll
            for (int off = 16; off > 0; off >>= 1) p += __shfl_xor(p, off, 32);
            if ((tid & 31) == 0) attn_s[j][tid >> 5] = p;
        }
    }
    __syncthreads();

    // --- phase B: masked softmax over j per head, scaled by sqrt(n)/16 ---
    {
        int hh = tid >> 5, j = tid & 31;
        float l = msk_s[j] ? attn_s[j][hh] : -1e9f;
        float mx = l;
        #pragma unroll
        for (int off = 16; off > 0; off >>= 1) mx = fmaxf(mx, __shfl_xor(mx, off, 32));
        float e0 = expf(l - mx);
        float ssum = e0;
        #pragma unroll
        for (int off = 16; off > 0; off >>= 1) ssum += __shfl_xor(ssum, off, 32);
        float wgt = (e0 / ssum) * norm_s;
        attn_s[j][hh] = wgt;
    }
    __syncthreads();

    // --- phase C: t_filt GEMM (j-groups of 16) + combine + j-reduction ---
    float acc_dh = 0.f;
    float acc1[3] = {0.f, 0.f, 0.f};
    float acc2[5] = {0.f, 0.f, 0.f, 0.f, 0.f};
    int hm[5];
    #pragma unroll
    for (int m = 0; m < 5; m++) hm[m] = (m*256 + tid) / 160;   // head of flat index

    const float* WrsT = ws + OFF_WRS;
    const float* Xp = ws + OFF_X + (size_t)(b*NN)*1280;
    const float* Vp = ws + OFF_V + (size_t)(b*NN)*1280;

    for (int p = 0; p < 2; p++) {
        const int j0 = p*16;
        float tf[16][5];
        #pragma unroll
        for (int jj = 0; jj < 16; jj++)
            #pragma unroll
            for (int m = 0; m < 5; m++) tf[jj][m] = 0.f;

        for (int e = 0; e < 256; e++) {
            float wm[5];
            #pragma unroll
            for (int m = 0; m < 5; m++) wm[m] = WrsT[e*1280 + m*256 + tid];
            #pragma unroll
            for (int jj = 0; jj < 16; jj++) {
                float tv = t_s[j0 + jj][e];
                #pragma unroll
                for (int m = 0; m < 5; m++) tf[jj][m] += tv * wm[m];
            }
        }

        for (int jj = 0; jj < 16; jj++) {
            const int j = j0 + jj;
            const int nb = nbr_s[j];
            const float cut = cut_s[j];
            const float* xr  = Xp + (size_t)nb*1280;
            const float* vr  = Vp + (size_t)nb*1280;
            const float* x1r = X1 + ((size_t)(b*NN + nb))*3*256;
            const float* x2r = X2 + ((size_t)(b*NN + nb))*5*256;
            #pragma unroll
            for (int m = 0; m < 5; m++) {
                float o = tf[jj][m] * xr[m*256 + tid] * cut
                        + attn_s[j][hm[m]] * vr[m*256 + tid];
                if (m == 0) {
                    acc_dh += o;
                } else if (m == 1) {
                    acc1[0] += r1_s[j][0]*o; acc1[1] += r1_s[j][1]*o; acc1[2] += r1_s[j][2]*o;
                } else if (m == 2) {
                    acc2[0] += r2_s[j][0]*o; acc2[1] += r2_s[j][1]*o; acc2[2] += r2_s[j][2]*o;
                    acc2[3] += r2_s[j][3]*o; acc2[4] += r2_s[j][4]*o;
                } else if (m == 3) {
                    acc1[0] += x1r[tid]*o; acc1[1] += x1r[256+tid]*o; acc1[2] += x1r[512+tid]*o;
                } else {
                    acc2[0] += x2r[tid]*o;     acc2[1] += x2r[256+tid]*o;
                    acc2[2] += x2r[512+tid]*o; acc2[3] += x2r[768+tid]*o;
                    acc2[4] += x2r[1024+tid]*o;
                }
            }
        }
    }

    // --- outputs: d_h | dX1 | dX2 concatenated ---
    out[(size_t)bi*256 + tid] = acc_dh;
    #pragma unroll
    for (int c = 0; c < 3; c++)
        out[262144 + ((size_t)bi*3 + c)*256 + tid] = acc1[c];
    #pragma unroll
    for (int c = 0; c < 5; c++)
        out[1048576 + ((size_t)bi*5 + c)*256 + tid] = acc2[c];
}

extern "C" void kernel_launch(void* const* d_in, const int* in_sizes, int n_in,
                              void* d_out, int out_size, void* d_ws, size_t ws_size,
                              hipStream_t stream) {
    const float* h    = (const float*)d_in[0];
    const float* X1   = (const float*)d_in[1];
    const float* X2   = (const float*)d_in[2];
    const float* r1   = (const float*)d_in[3];
    const float* r2   = (const float*)d_in[4];
    const float* t_ij = (const float*)d_in[5];
    const float* r_ij = (const float*)d_in[6];
    const int*   nbr  = (const int*)d_in[7];
    const unsigned int* mask_raw = (const unsigned int*)d_in[8];
    const float* ln_w = (const float*)d_in[9];
    const float* ln_b = (const float*)d_in[10];
    const float* Wq   = (const float*)d_in[11];
    const float* Wk   = (const float*)d_in[12];
    const float* Wre  = (const float*)d_in[13];
    const float* Wrs  = (const float*)d_in[14];
    const float* gs1  = (const float*)d_in[15];
    const float* gs2  = (const float*)d_in[16];
    const float* gv1  = (const float*)d_in[17];
    const float* gv2  = (const float*)d_in[18];

    float* ws  = (float*)d_ws;
    float* out = (float*)d_out;

    hipLaunchKernelGGL(mask_norm_kernel, dim3(1), dim3(256), 0, stream,
                       mask_raw, (unsigned char*)(ws + OFF_MSK));
    hipLaunchKernelGGL(transpose_kernel, dim3(5120), dim3(256), 0, stream,
                       Wq, Wk, gs1, gv1, Wre, gs2, gv2, Wrs, ws);
    hipLaunchKernelGGL(node_kernel, dim3(BB*NN/8), dim3(256), 0, stream,
                       h, ln_w, ln_b, ws);
    hipLaunchKernelGGL(edge_kernel, dim3(BB*NN), dim3(256), 0, stream,
                       t_ij, r_ij, nbr, r1, r2, X1, X2, ws, out);
}

// Round 4
// 1333.344 us; speedup vs baseline: 1.2480x; 1.2480x over previous
//
#include <hip/hip_runtime.h>

#define BB 2
#define NN 512
#define JJ 32
#define DD 256
#define HH 8
#define MM 5
#define MD 1280

// workspace layout (float offsets)
#define OFF_WQ   0          // 256x256 transposed
#define OFF_WK   65536
#define OFF_GS1  131072
#define OFF_GV1  196608
#define OFF_WRE  262144
#define OFF_GS2  327680     // 256x1280 transposed
#define OFF_GV2  655360
#define OFF_WRS  983040
#define OFF_Q    1310720    // B*N*D
#define OFF_K    1572864
#define OFF_X    1835008    // B*N*MD
#define OFF_V    3145728
#define OFF_MSK  4456448    // normalized mask bytes (8192 floats)
#define OFF_ATTN 4464640    // attn weights [1024][32][8], pre-scaled by norm
// total 4726784 floats = 18.9 MB

__device__ __forceinline__ float silu_f(float x){ return x / (1.0f + expf(-x)); }

// ---------------- mask normalization (8 blocks; per-block layout detect) ----------------
__global__ void mask_norm_kernel(const unsigned int* __restrict__ raw,
                                 unsigned char* __restrict__ outm) {
    __shared__ int flag_s;
    const int tid = threadIdx.x;
    const int blk = blockIdx.x;              // 8 blocks
    if (tid == 0) flag_s = 0;
    __syncthreads();
    // scan this block's 1024-word slice of the first 8192 words (in-bounds either layout)
    int bad = 0;
    for (int i = tid; i < 1024; i += 256) bad |= (raw[blk*1024 + i] > 1u) ? 1 : 0;
    if (bad) atomicOr(&flag_s, 1);
    __syncthreads();
    const int base = blk * 4096;             // byte-index region
    if (flag_s) {   // byte layout
        const unsigned char* rb = (const unsigned char*)raw;
        for (int i = tid; i < 4096; i += 256) outm[base + i] = rb[base + i] ? 1 : 0;
    } else {        // int32 layout
        for (int i = tid; i < 4096; i += 256) outm[base + i] = raw[base + i] ? 1 : 0;
    }
}

// ---------------- LDS-tiled weight transpose (coalesced both sides) ----------------
__global__ __launch_bounds__(256) void transpose_kernel(
        const float* __restrict__ Wq, const float* __restrict__ Wk,
        const float* __restrict__ gs1, const float* __restrict__ gv1,
        const float* __restrict__ Wre, const float* __restrict__ gs2,
        const float* __restrict__ gv2, const float* __restrict__ Wrs,
        float* __restrict__ ws) {
    __shared__ float tile[32][33];
    const int bid = blockIdx.x;              // 1280 tiles
    const float* src; float* dst; int R, tr, tc;
    if (bid < 320) {                          // 5 square matrices, 64 tiles each
        int m = bid >> 6, t = bid & 63;
        tr = t >> 3; tc = t & 7; R = 256;
        src = (m==0)?Wq:(m==1)?Wk:(m==2)?gs1:(m==3)?gv1:Wre;
        dst = ws + m*65536;
    } else {                                  // 3 big (1280x256), 320 tiles each
        int b2 = bid - 320;
        int m = b2 / 320, t = b2 % 320;
        tr = t >> 3; tc = t & 7; R = 1280;
        src = (m==0)?gs2:(m==1)?gv2:Wrs;
        dst = ws + OFF_GS2 + m*327680;
    }
    const int r = threadIdx.x >> 5, c = threadIdx.x & 31;
    #pragma unroll
    for (int s = 0; s < 4; s++)
        tile[r + 8*s][c] = src[(size_t)(tr*32 + r + 8*s)*256 + tc*32 + c];
    __syncthreads();
    #pragma unroll
    for (int s = 0; s < 4; s++)
        dst[(size_t)(tc*32 + r + 8*s)*R + tr*32 + c] = tile[c][r + 8*s];
}

// ---------------- node kernel: LN + q,k + gated MLPs (4 rows/block) ----------------
__global__ __launch_bounds__(256) void node_kernel(const float* __restrict__ h,
                                                   const float* __restrict__ ln_w,
                                                   const float* __restrict__ ln_b,
                                                   float* __restrict__ ws) {
    __shared__ float hs[4][256];
    __shared__ float s1s[4][256];
    __shared__ float v1s[4][256];
    __shared__ float mu_s[4], rstd_s[4];
    const int tid = threadIdx.x;
    const int row0 = blockIdx.x * 4;

    #pragma unroll
    for (int r = 0; r < 4; r++) hs[r][tid] = h[(size_t)(row0 + r)*256 + tid];
    __syncthreads();

    {   // layernorm: 64-lane group g reduces row g
        int g = tid >> 6, l = tid & 63;
        float s = 0.f;
        #pragma unroll
        for (int k = 0; k < 4; k++) s += hs[g][l + 64*k];
        #pragma unroll
        for (int off = 32; off > 0; off >>= 1) s += __shfl_xor(s, off, 64);
        float mu = s * (1.0f/256.0f);
        float v = 0.f;
        #pragma unroll
        for (int k = 0; k < 4; k++) { float d0 = hs[g][l + 64*k] - mu; v += d0*d0; }
        #pragma unroll
        for (int off = 32; off > 0; off >>= 1) v += __shfl_xor(v, off, 64);
        if (l == 0) { mu_s[g] = mu; rstd_s[g] = rsqrtf(v*(1.0f/256.0f) + 1e-5f); }
    }
    __syncthreads();
    {
        float w = ln_w[tid], bb = ln_b[tid];
        #pragma unroll
        for (int r = 0; r < 4; r++) hs[r][tid] = (hs[r][tid] - mu_s[r]) * rstd_s[r] * w + bb;
    }
    __syncthreads();

    {   // stage 1
        float aq[4], ak[4], a1[4], a2[4];
        #pragma unroll
        for (int r = 0; r < 4; r++) { aq[r]=0.f; ak[r]=0.f; a1[r]=0.f; a2[r]=0.f; }
        const float* WqT  = ws + OFF_WQ;
        const float* WkT  = ws + OFF_WK;
        const float* G1T  = ws + OFF_GS1;
        const float* Gv1T = ws + OFF_GV1;
        for (int e = 0; e < 256; e++) {
            float wq = WqT[e*256 + tid];
            float wk = WkT[e*256 + tid];
            float w1 = G1T[e*256 + tid];
            float w2 = Gv1T[e*256 + tid];
            #pragma unroll
            for (int r = 0; r < 4; r++) {
                float hv = hs[r][e];
                aq[r] += hv*wq; ak[r] += hv*wk; a1[r] += hv*w1; a2[r] += hv*w2;
            }
        }
        #pragma unroll
        for (int r = 0; r < 4; r++) {
            ws[OFF_Q + (size_t)(row0 + r)*256 + tid] = aq[r];
            ws[OFF_K + (size_t)(row0 + r)*256 + tid] = ak[r];
            s1s[r][tid] = silu_f(a1[r]);
            v1s[r][tid] = silu_f(a2[r]);
        }
    }
    __syncthreads();

    {   // stage 2
        float ax[4][5], av[4][5];
        #pragma unroll
        for (int r = 0; r < 4; r++)
            #pragma unroll
            for (int m = 0; m < 5; m++) { ax[r][m]=0.f; av[r][m]=0.f; }
        const float* G2T  = ws + OFF_GS2;
        const float* Gv2T = ws + OFF_GV2;
        for (int e = 0; e < 256; e++) {
            float wx[5], wv[5];
            #pragma unroll
            for (int m = 0; m < 5; m++) {
                wx[m] = G2T [e*1280 + m*256 + tid];
                wv[m] = Gv2T[e*1280 + m*256 + tid];
            }
            #pragma unroll
            for (int r = 0; r < 4; r++) {
                float s1v = s1s[r][e], v1v = v1s[r][e];
                #pragma unroll
                for (int m = 0; m < 5; m++) { ax[r][m] += s1v*wx[m]; av[r][m] += v1v*wv[m]; }
            }
        }
        #pragma unroll
        for (int r = 0; r < 4; r++)
            #pragma unroll
            for (int m = 0; m < 5; m++) {
                ws[OFF_X + (size_t)(row0 + r)*1280 + m*256 + tid] = ax[r][m];
                ws[OFF_V + (size_t)(row0 + r)*1280 + m*256 + tid] = av[r][m];
            }
    }
}

// ---------------- attn kernel: phases A+B, writes pre-scaled weights ----------------
__global__ __launch_bounds__(256) void attn_kernel(const float* __restrict__ t_ij,
                                                   const int* __restrict__ nbr,
                                                   float* __restrict__ ws) {
    __shared__ float t_s[JJ][DD];     // 32 KB
    __shared__ float q_s[DD];
    __shared__ float attn_s[JJ][HH];
    __shared__ int   nbr_s[JJ];
    __shared__ int   msk_s[JJ];
    __shared__ float norm_s;

    const int tid = threadIdx.x;
    const int bi  = blockIdx.x;
    const int b   = bi >> 9;
    const unsigned char* mask = (const unsigned char*)(ws + OFF_MSK);

    if (tid < JJ) {
        nbr_s[tid] = nbr[bi*JJ + tid];
        msk_s[tid] = mask[bi*JJ + tid] ? 1 : 0;
    }
    q_s[tid] = ws[OFF_Q + (size_t)bi*256 + tid];
    for (int j = 0; j < JJ; j++)
        t_s[j][tid] = t_ij[((size_t)bi*JJ + j)*256 + tid];
    __syncthreads();
    if (tid == 0) {
        int n = 0;
        for (int j = 0; j < JJ; j++) n += msk_s[j];
        norm_s = sqrtf((float)n) * (1.0f/16.0f);
    }

    // t_attn column tid for all 32 j
    float ta[JJ];
    #pragma unroll
    for (int j = 0; j < JJ; j++) ta[j] = 0.f;
    {
        const float* WreT = ws + OFF_WRE;
        for (int e = 0; e < 256; e += 4) {
            float w4[4];
            #pragma unroll
            for (int s = 0; s < 4; s++) w4[s] = WreT[(e+s)*256 + tid];
            #pragma unroll
            for (int j = 0; j < JJ; j++) {
                const float4 tv = *reinterpret_cast<const float4*>(&t_s[j][e]);
                ta[j] += tv.x*w4[0] + tv.y*w4[1] + tv.z*w4[2] + tv.w*w4[3];
            }
        }
    }
    {
        float qv = q_s[tid];
        #pragma unroll
        for (int j = 0; j < JJ; j++) {
            float kv = ws[OFF_K + (size_t)(b*NN + nbr_s[j])*256 + tid];
            float p = qv * kv * silu_f(ta[j]);
            #pragma unroll
            for (int off = 16; off > 0; off >>= 1) p += __shfl_xor(p, off, 32);
            if ((tid & 31) == 0) attn_s[j][tid >> 5] = p;
        }
    }
    __syncthreads();
    {   // masked softmax + scale, write to ws
        int hh = tid >> 5, j = tid & 31;
        float l = msk_s[j] ? attn_s[j][hh] : -1e9f;
        float mx = l;
        #pragma unroll
        for (int off = 16; off > 0; off >>= 1) mx = fmaxf(mx, __shfl_xor(mx, off, 32));
        float e0 = expf(l - mx);
        float ssum = e0;
        #pragma unroll
        for (int off = 16; off > 0; off >>= 1) ssum += __shfl_xor(ssum, off, 32);
        ws[OFF_ATTN + (size_t)bi*256 + j*8 + hh] = (e0 / ssum) * norm_s;
    }
}

// ---------------- combine kernel: t_filt GEMM slice + combine + j-reduce ----------------
// G=0: m={0} -> d_h ; G=1: m={1,3} -> dX1 ; G=2: m={2,4} -> dX2
template<int G>
__global__ __launch_bounds__(256, 3) void combine_kernel(
        const float* __restrict__ t_ij, const float* __restrict__ r_ij,
        const int* __restrict__ nbr,
        const float* __restrict__ r1, const float* __restrict__ r2,
        const float* __restrict__ X1, const float* __restrict__ X2,
        const float* __restrict__ ws, float* __restrict__ out) {
    __shared__ float t_s[JJ][DD];     // 32 KB
    __shared__ float attn_l[JJ][HH];
    __shared__ float cut_s[JJ];
    __shared__ float r1_s[JJ][3];
    __shared__ float r2_s[JJ][5];
    __shared__ int   nbr_s[JJ];

    const int tid = threadIdx.x;
    const int bi  = blockIdx.x;
    const int b   = bi >> 9;

    if (tid < JJ) {
        int eidx = bi*JJ + tid;
        nbr_s[tid] = nbr[eidx];
        float r = r_ij[eidx];
        cut_s[tid] = (r < 5.0f) ? 0.5f*(cosf(r * 0.62831853071795864f) + 1.0f) : 0.0f;
        #pragma unroll
        for (int c = 0; c < 3; c++) r1_s[tid][c] = r1[eidx*3 + c];
        #pragma unroll
        for (int c = 0; c < 5; c++) r2_s[tid][c] = r2[eidx*5 + c];
    }
    attn_l[tid >> 3][tid & 7] = ws[OFF_ATTN + (size_t)bi*256 + tid];
    for (int j = 0; j < JJ; j++)
        t_s[j][tid] = t_ij[((size_t)bi*JJ + j)*256 + tid];
    __syncthreads();

    constexpr int m0 = (G == 0) ? 0 : (G == 1) ? 1 : 2;
    constexpr int m1 = m0 + 2;   // used when G>0

    // t_filt slices for this group's m's, all 32 j at once
    float tf0[JJ];
    float tf1[JJ];
    #pragma unroll
    for (int j = 0; j < JJ; j++) { tf0[j] = 0.f; if (G > 0) tf1[j] = 0.f; }
    {
        const float* W0 = ws + OFF_WRS + m0*256 + tid;
        const float* W1 = ws + OFF_WRS + m1*256 + tid;
        for (int e = 0; e < 256; e += 4) {
            float wa[4], wb[4];
            #pragma unroll
            for (int s = 0; s < 4; s++) wa[s] = W0[(size_t)(e+s)*1280];
            if (G > 0) {
                #pragma unroll
                for (int s = 0; s < 4; s++) wb[s] = W1[(size_t)(e+s)*1280];
            }
            #pragma unroll
            for (int j = 0; j < JJ; j++) {
                const float4 tv = *reinterpret_cast<const float4*>(&t_s[j][e]);
                tf0[j] += tv.x*wa[0] + tv.y*wa[1] + tv.z*wa[2] + tv.w*wa[3];
                if (G > 0)
                    tf1[j] += tv.x*wb[0] + tv.y*wb[1] + tv.z*wb[2] + tv.w*wb[3];
            }
        }
    }

    // combine + j-reduction
    const float* Xb = ws + OFF_X + (size_t)b*NN*1280;
    const float* Vb = ws + OFF_V + (size_t)b*NN*1280;
    const int h0 = (m0*256 + tid) / 160;
    const int h1 = (m1*256 + tid) / 160;
    float acc[5] = {0.f, 0.f, 0.f, 0.f, 0.f};

    #pragma unroll 4
    for (int j = 0; j < JJ; j++) {
        const int nb = nbr_s[j];
        const float cut = cut_s[j];
        const float* xr = Xb + (size_t)nb*1280;
        const float* vr = Vb + (size_t)nb*1280;
        float o0 = tf0[j]*xr[m0*256 + tid]*cut + attn_l[j][h0]*vr[m0*256 + tid];
        if (G == 0) {
            acc[0] += o0;
        } else {
            float o1 = tf1[j]*xr[m1*256 + tid]*cut + attn_l[j][h1]*vr[m1*256 + tid];
            if (G == 1) {
                const float* x1r = X1 + ((size_t)(b*NN + nb))*768;
                acc[0] += r1_s[j][0]*o0 + x1r[tid]*o1;
                acc[1] += r1_s[j][1]*o0 + x1r[256 + tid]*o1;
                acc[2] += r1_s[j][2]*o0 + x1r[512 + tid]*o1;
            } else {
                const float* x2r = X2 + ((size_t)(b*NN + nb))*1280;
                #pragma unroll
                for (int c = 0; c < 5; c++)
                    acc[c] += r2_s[j][c]*o0 + x2r[c*256 + tid]*o1;
            }
        }
    }

    if (G == 0) {
        out[(size_t)bi*256 + tid] = acc[0];
    } else if (G == 1) {
        #pragma unroll
        for (int c = 0; c < 3; c++)
            out[262144 + ((size_t)bi*3 + c)*256 + tid] = acc[c];
    } else {
        #pragma unroll
        for (int c = 0; c < 5; c++)
            out[1048576 + ((size_t)bi*5 + c)*256 + tid] = acc[c];
    }
}

extern "C" void kernel_launch(void* const* d_in, const int* in_sizes, int n_in,
                              void* d_out, int out_size, void* d_ws, size_t ws_size,
                              hipStream_t stream) {
    const float* h    = (const float*)d_in[0];
    const float* X1   = (const float*)d_in[1];
    const float* X2   = (const float*)d_in[2];
    const float* r1   = (const float*)d_in[3];
    const float* r2   = (const float*)d_in[4];
    const float* t_ij = (const float*)d_in[5];
    const float* r_ij = (const float*)d_in[6];
    const int*   nbr  = (const int*)d_in[7];
    const unsigned int* mask_raw = (const unsigned int*)d_in[8];
    const float* ln_w = (const float*)d_in[9];
    const float* ln_b = (const float*)d_in[10];
    const float* Wq   = (const float*)d_in[11];
    const float* Wk   = (const float*)d_in[12];
    const float* Wre  = (const float*)d_in[13];
    const float* Wrs  = (const float*)d_in[14];
    const float* gs1  = (const float*)d_in[15];
    const float* gs2  = (const float*)d_in[16];
    const float* gv1  = (const float*)d_in[17];
    const float* gv2  = (const float*)d_in[18];

    float* ws  = (float*)d_ws;
    float* out = (float*)d_out;

    hipLaunchKernelGGL(mask_norm_kernel, dim3(8), dim3(256), 0, stream,
                       mask_raw, (unsigned char*)(ws + OFF_MSK));
    hipLaunchKernelGGL(transpose_kernel, dim3(1280), dim3(256), 0, stream,
                       Wq, Wk, gs1, gv1, Wre, gs2, gv2, Wrs, ws);
    hipLaunchKernelGGL(node_kernel, dim3(BB*NN/4), dim3(256), 0, stream,
                       h, ln_w, ln_b, ws);
    hipLaunchKernelGGL(attn_kernel, dim3(BB*NN), dim3(256), 0, stream,
                       t_ij, nbr, ws);
    hipLaunchKernelGGL((combine_kernel<0>), dim3(BB*NN), dim3(256), 0, stream,
                       t_ij, r_ij, nbr, r1, r2, X1, X2, ws, out);
    hipLaunchKernelGGL((combine_kernel<1>), dim3(BB*NN), dim3(256), 0, stream,
                       t_ij, r_ij, nbr, r1, r2, X1, X2, ws, out);
    hipLaunchKernelGGL((combine_kernel<2>), dim3(BB*NN), dim3(256), 0, stream,
                       t_ij, r_ij, nbr, r1, r2, X1, X2, ws, out);
}

// Round 6
// 811.165 us; speedup vs baseline: 2.0514x; 1.6437x over previous
//
#include <hip/hip_runtime.h>

#define BB 2
#define NN 512
#define JJ 32
#define DD 256
#define HH 8
#define MM 5
#define MD 1280

// workspace layout (float offsets)
#define OFF_WQ   0          // 256x256 transposed
#define OFF_WK   65536
#define OFF_GS1  131072
#define OFF_GV1  196608
#define OFF_WRE  262144
#define OFF_GS2  327680     // 256x1280 transposed
#define OFF_GV2  655360
#define OFF_WRS  983040
#define OFF_Q    1310720    // B*N*D
#define OFF_K    1572864
#define OFF_X    1835008    // B*N*MD
#define OFF_V    3145728
#define OFF_MSK  4456448    // normalized mask bytes (8192 floats)
#define OFF_ATTN 4464640    // attn weights [1024][32][8], pre-scaled by norm
// total 4726784 floats = 18.9 MB

__device__ __forceinline__ float silu_f(float x){ return x / (1.0f + expf(-x)); }

// ---------------- mask normalization (8 blocks; per-block layout detect) ----------------
__global__ void mask_norm_kernel(const unsigned int* __restrict__ raw,
                                 unsigned char* __restrict__ outm) {
    __shared__ int flag_s;
    const int tid = threadIdx.x;
    const int blk = blockIdx.x;              // 8 blocks
    if (tid == 0) flag_s = 0;
    __syncthreads();
    int bad = 0;
    for (int i = tid; i < 1024; i += 256) bad |= (raw[blk*1024 + i] > 1u) ? 1 : 0;
    if (bad) atomicOr(&flag_s, 1);
    __syncthreads();
    const int base = blk * 4096;             // byte-index region
    if (flag_s) {   // byte layout
        const unsigned char* rb = (const unsigned char*)raw;
        for (int i = tid; i < 4096; i += 256) outm[base + i] = rb[base + i] ? 1 : 0;
    } else {        // int32 layout
        for (int i = tid; i < 4096; i += 256) outm[base + i] = raw[base + i] ? 1 : 0;
    }
}

// ---------------- LDS-tiled weight transpose (coalesced both sides) ----------------
__global__ __launch_bounds__(256) void transpose_kernel(
        const float* __restrict__ Wq, const float* __restrict__ Wk,
        const float* __restrict__ gs1, const float* __restrict__ gv1,
        const float* __restrict__ Wre, const float* __restrict__ gs2,
        const float* __restrict__ gv2, const float* __restrict__ Wrs,
        float* __restrict__ ws) {
    __shared__ float tile[32][33];
    const int bid = blockIdx.x;              // 1280 tiles
    const float* src; float* dst; int R, tr, tc;
    if (bid < 320) {                          // 5 square matrices, 64 tiles each
        int m = bid >> 6, t = bid & 63;
        tr = t >> 3; tc = t & 7; R = 256;
        src = (m==0)?Wq:(m==1)?Wk:(m==2)?gs1:(m==3)?gv1:Wre;
        dst = ws + m*65536;
    } else {                                  // 3 big (1280x256), 320 tiles each
        int b2 = bid - 320;
        int m = b2 / 320, t = b2 % 320;
        tr = t >> 3; tc = t & 7; R = 1280;
        src = (m==0)?gs2:(m==1)?gv2:Wrs;
        dst = ws + OFF_GS2 + m*327680;
    }
    const int r = threadIdx.x >> 5, c = threadIdx.x & 31;
    #pragma unroll
    for (int s = 0; s < 4; s++)
        tile[r + 8*s][c] = src[(size_t)(tr*32 + r + 8*s)*256 + tc*32 + c];
    __syncthreads();
    #pragma unroll
    for (int s = 0; s < 4; s++)
        dst[(size_t)(tc*32 + r + 8*s)*R + tr*32 + c] = tile[c][r + 8*s];
}

// ---------------- node kernel: LN + q,k + gated MLPs (4 rows/block) ----------------
__global__ __launch_bounds__(256) void node_kernel(const float* __restrict__ h,
                                                   const float* __restrict__ ln_w,
                                                   const float* __restrict__ ln_b,
                                                   float* __restrict__ ws) {
    __shared__ float hs[4][256];
    __shared__ float s1s[4][256];
    __shared__ float v1s[4][256];
    __shared__ float mu_s[4], rstd_s[4];
    const int tid = threadIdx.x;
    const int row0 = blockIdx.x * 4;

    #pragma unroll
    for (int r = 0; r < 4; r++) hs[r][tid] = h[(size_t)(row0 + r)*256 + tid];
    __syncthreads();

    {   // layernorm: 64-lane group g reduces row g
        int g = tid >> 6, l = tid & 63;
        float s = 0.f;
        #pragma unroll
        for (int k = 0; k < 4; k++) s += hs[g][l + 64*k];
        #pragma unroll
        for (int off = 32; off > 0; off >>= 1) s += __shfl_xor(s, off, 64);
        float mu = s * (1.0f/256.0f);
        float v = 0.f;
        #pragma unroll
        for (int k = 0; k < 4; k++) { float d0 = hs[g][l + 64*k] - mu; v += d0*d0; }
        #pragma unroll
        for (int off = 32; off > 0; off >>= 1) v += __shfl_xor(v, off, 64);
        if (l == 0) { mu_s[g] = mu; rstd_s[g] = rsqrtf(v*(1.0f/256.0f) + 1e-5f); }
    }
    __syncthreads();
    {
        float w = ln_w[tid], bb = ln_b[tid];
        #pragma unroll
        for (int r = 0; r < 4; r++) hs[r][tid] = (hs[r][tid] - mu_s[r]) * rstd_s[r] * w + bb;
    }
    __syncthreads();

    {   // stage 1
        float aq[4], ak[4], a1[4], a2[4];
        #pragma unroll
        for (int r = 0; r < 4; r++) { aq[r]=0.f; ak[r]=0.f; a1[r]=0.f; a2[r]=0.f; }
        const float* WqT  = ws + OFF_WQ;
        const float* WkT  = ws + OFF_WK;
        const float* G1T  = ws + OFF_GS1;
        const float* Gv1T = ws + OFF_GV1;
        for (int e = 0; e < 256; e++) {
            float wq = WqT[e*256 + tid];
            float wk = WkT[e*256 + tid];
            float w1 = G1T[e*256 + tid];
            float w2 = Gv1T[e*256 + tid];
            #pragma unroll
            for (int r = 0; r < 4; r++) {
                float hv = hs[r][e];
                aq[r] += hv*wq; ak[r] += hv*wk; a1[r] += hv*w1; a2[r] += hv*w2;
            }
        }
        #pragma unroll
        for (int r = 0; r < 4; r++) {
            ws[OFF_Q + (size_t)(row0 + r)*256 + tid] = aq[r];
            ws[OFF_K + (size_t)(row0 + r)*256 + tid] = ak[r];
            s1s[r][tid] = silu_f(a1[r]);
            v1s[r][tid] = silu_f(a2[r]);
        }
    }
    __syncthreads();

    {   // stage 2
        float ax[4][5], av[4][5];
        #pragma unroll
        for (int r = 0; r < 4; r++)
            #pragma unroll
            for (int m = 0; m < 5; m++) { ax[r][m]=0.f; av[r][m]=0.f; }
        const float* G2T  = ws + OFF_GS2;
        const float* Gv2T = ws + OFF_GV2;
        for (int e = 0; e < 256; e++) {
            float wx[5], wv[5];
            #pragma unroll
            for (int m = 0; m < 5; m++) {
                wx[m] = G2T [e*1280 + m*256 + tid];
                wv[m] = Gv2T[e*1280 + m*256 + tid];
            }
            #pragma unroll
            for (int r = 0; r < 4; r++) {
                float s1v = s1s[r][e], v1v = v1s[r][e];
                #pragma unroll
                for (int m = 0; m < 5; m++) { ax[r][m] += s1v*wx[m]; av[r][m] += v1v*wv[m]; }
            }
        }
        #pragma unroll
        for (int r = 0; r < 4; r++)
            #pragma unroll
            for (int m = 0; m < 5; m++) {
                ws[OFF_X + (size_t)(row0 + r)*1280 + m*256 + tid] = ax[r][m];
                ws[OFF_V + (size_t)(row0 + r)*1280 + m*256 + tid] = av[r][m];
            }
    }
}

// ---------------- attn kernel: phases A+B, writes pre-scaled weights ----------------
__global__ __launch_bounds__(256) void attn_kernel(const float* __restrict__ t_ij,
                                                   const int* __restrict__ nbr,
                                                   float* __restrict__ ws) {
    __shared__ float t_s[JJ][DD];     // 32 KB
    __shared__ float q_s[DD];
    __shared__ float attn_s[JJ][HH];
    __shared__ int   nbr_s[JJ];
    __shared__ int   msk_s[JJ];
    __shared__ float norm_s;

    const int tid = threadIdx.x;
    const int bi  = blockIdx.x;
    const int b   = bi >> 9;
    const unsigned char* mask = (const unsigned char*)(ws + OFF_MSK);

    if (tid < JJ) {
        nbr_s[tid] = nbr[bi*JJ + tid];
        msk_s[tid] = mask[bi*JJ + tid] ? 1 : 0;
    }
    q_s[tid] = ws[OFF_Q + (size_t)bi*256 + tid];
    for (int j = 0; j < JJ; j++)
        t_s[j][tid] = t_ij[((size_t)bi*JJ + j)*256 + tid];
    __syncthreads();
    if (tid == 0) {
        int n = 0;
        for (int j = 0; j < JJ; j++) n += msk_s[j];
        norm_s = sqrtf((float)n) * (1.0f/16.0f);
    }

    // t_attn column tid for all 32 j
    float ta[JJ];
    #pragma unroll
    for (int j = 0; j < JJ; j++) ta[j] = 0.f;
    {
        const float* WreT = ws + OFF_WRE;
        for (int e = 0; e < 256; e += 4) {
            float w4[4];
            #pragma unroll
            for (int s = 0; s < 4; s++) w4[s] = WreT[(e+s)*256 + tid];
            #pragma unroll
            for (int j = 0; j < JJ; j++) {
                const float4 tv = *reinterpret_cast<const float4*>(&t_s[j][e]);
                ta[j] += tv.x*w4[0] + tv.y*w4[1] + tv.z*w4[2] + tv.w*w4[3];
            }
        }
    }
    {
        float qv = q_s[tid];
        #pragma unroll
        for (int j = 0; j < JJ; j++) {
            float kv = ws[OFF_K + (size_t)(b*NN + nbr_s[j])*256 + tid];
            float p = qv * kv * silu_f(ta[j]);
            #pragma unroll
            for (int off = 16; off > 0; off >>= 1) p += __shfl_xor(p, off, 32);
            if ((tid & 31) == 0) attn_s[j][tid >> 5] = p;
        }
    }
    __syncthreads();
    {   // masked softmax + scale, write to ws
        int hh = tid >> 5, j = tid & 31;
        float l = msk_s[j] ? attn_s[j][hh] : -1e9f;
        float mx = l;
        #pragma unroll
        for (int off = 16; off > 0; off >>= 1) mx = fmaxf(mx, __shfl_xor(mx, off, 32));
        float e0 = expf(l - mx);
        float ssum = e0;
        #pragma unroll
        for (int off = 16; off > 0; off >>= 1) ssum += __shfl_xor(ssum, off, 32);
        ws[OFF_ATTN + (size_t)bi*256 + j*8 + hh] = (e0 / ssum) * norm_s;
    }
}

// ---------------- combine kernel: t_filt GEMM slice + combine + j-reduce ----------------
// G=0: m={0} -> d_h ; G=1: m={1,3} -> dX1 ; G=2: m={2,4} -> dX2
// NOTE: the combine j-loop MUST be fully unrolled — a runtime j index into
// tf0/tf1 demotes them to scratch (rule #20; cost measured: 1.85 GB scratch
// writes, 688 us -> this kernel was 52% of round-4 runtime).
template<int G>
__global__ __launch_bounds__(256, 3) void combine_kernel(
        const float* __restrict__ t_ij, const float* __restrict__ r_ij,
        const int* __restrict__ nbr,
        const float* __restrict__ r1, const float* __restrict__ r2,
        const float* __restrict__ X1, const float* __restrict__ X2,
        const float* __restrict__ ws, float* __restrict__ out) {
    __shared__ float t_s[JJ][DD];     // 32 KB
    __shared__ float attn_l[JJ][HH];
    __shared__ float cut_s[JJ];
    __shared__ float r1_s[JJ][3];
    __shared__ float r2_s[JJ][5];
    __shared__ int   nbr_s[JJ];

    const int tid = threadIdx.x;
    const int bi  = blockIdx.x;
    const int b   = bi >> 9;

    if (tid < JJ) {
        int eidx = bi*JJ + tid;
        nbr_s[tid] = nbr[eidx];
        float r = r_ij[eidx];
        cut_s[tid] = (r < 5.0f) ? 0.5f*(cosf(r * 0.62831853071795864f) + 1.0f) : 0.0f;
        #pragma unroll
        for (int c = 0; c < 3; c++) r1_s[tid][c] = r1[eidx*3 + c];
        #pragma unroll
        for (int c = 0; c < 5; c++) r2_s[tid][c] = r2[eidx*5 + c];
    }
    attn_l[tid >> 3][tid & 7] = ws[OFF_ATTN + (size_t)bi*256 + tid];
    for (int j = 0; j < JJ; j++)
        t_s[j][tid] = t_ij[((size_t)bi*JJ + j)*256 + tid];
    __syncthreads();

    constexpr int m0 = (G == 0) ? 0 : (G == 1) ? 1 : 2;
    constexpr int m1 = m0 + 2;   // used when G>0

    // t_filt slices for this group's m's, all 32 j at once
    float tf0[JJ];
    float tf1[JJ];
    #pragma unroll
    for (int j = 0; j < JJ; j++) { tf0[j] = 0.f; if (G > 0) tf1[j] = 0.f; }
    {
        const float* W0 = ws + OFF_WRS + m0*256 + tid;
        const float* W1 = ws + OFF_WRS + m1*256 + tid;
        for (int e = 0; e < 256; e += 4) {
            float wa[4], wb[4];
            #pragma unroll
            for (int s = 0; s < 4; s++) wa[s] = W0[(size_t)(e+s)*1280];
            if (G > 0) {
                #pragma unroll
                for (int s = 0; s < 4; s++) wb[s] = W1[(size_t)(e+s)*1280];
            }
            #pragma unroll
            for (int j = 0; j < JJ; j++) {
                const float4 tv = *reinterpret_cast<const float4*>(&t_s[j][e]);
                tf0[j] += tv.x*wa[0] + tv.y*wa[1] + tv.z*wa[2] + tv.w*wa[3];
                if (G > 0)
                    tf1[j] += tv.x*wb[0] + tv.y*wb[1] + tv.z*wb[2] + tv.w*wb[3];
            }
        }
    }

    // combine + j-reduction (FULL unroll: tf0/tf1 must stay in registers)
    const float* Xb = ws + OFF_X + (size_t)b*NN*1280;
    const float* Vb = ws + OFF_V + (size_t)b*NN*1280;
    const int h0 = (m0*256 + tid) / 160;
    const int h1 = (m1*256 + tid) / 160;
    float acc[5] = {0.f, 0.f, 0.f, 0.f, 0.f};

    #pragma unroll
    for (int j = 0; j < JJ; j++) {
        const int nb = nbr_s[j];
        const float cut = cut_s[j];
        const float* xr = Xb + (size_t)nb*1280;
        const float* vr = Vb + (size_t)nb*1280;
        float o0 = tf0[j]*xr[m0*256 + tid]*cut + attn_l[j][h0]*vr[m0*256 + tid];
        if (G == 0) {
            acc[0] += o0;
        } else {
            float o1 = tf1[j]*xr[m1*256 + tid]*cut + attn_l[j][h1]*vr[m1*256 + tid];
            if (G == 1) {
                const float* x1r = X1 + ((size_t)(b*NN + nb))*768;
                acc[0] += r1_s[j][0]*o0 + x1r[tid]*o1;
                acc[1] += r1_s[j][1]*o0 + x1r[256 + tid]*o1;
                acc[2] += r1_s[j][2]*o0 + x1r[512 + tid]*o1;
            } else {
                const float* x2r = X2 + ((size_t)(b*NN + nb))*1280;
                #pragma unroll
                for (int c = 0; c < 5; c++)
                    acc[c] += r2_s[j][c]*o0 + x2r[c*256 + tid]*o1;
            }
        }
    }

    if (G == 0) {
        out[(size_t)bi*256 + tid] = acc[0];
    } else if (G == 1) {
        #pragma unroll
        for (int c = 0; c < 3; c++)
            out[262144 + ((size_t)bi*3 + c)*256 + tid] = acc[c];
    } else {
        #pragma unroll
        for (int c = 0; c < 5; c++)
            out[1048576 + ((size_t)bi*5 + c)*256 + tid] = acc[c];
    }
}

extern "C" void kernel_launch(void* const* d_in, const int* in_sizes, int n_in,
                              void* d_out, int out_size, void* d_ws, size_t ws_size,
                              hipStream_t stream) {
    const float* h    = (const float*)d_in[0];
    const float* X1   = (const float*)d_in[1];
    const float* X2   = (const float*)d_in[2];
    const float* r1   = (const float*)d_in[3];
    const float* r2   = (const float*)d_in[4];
    const float* t_ij = (const float*)d_in[5];
    const float* r_ij = (const float*)d_in[6];
    const int*   nbr  = (const int*)d_in[7];
    const unsigned int* mask_raw = (const unsigned int*)d_in[8];
    const float* ln_w = (const float*)d_in[9];
    const float* ln_b = (const float*)d_in[10];
    const float* Wq   = (const float*)d_in[11];
    const float* Wk   = (const float*)d_in[12];
    const float* Wre  = (const float*)d_in[13];
    const float* Wrs  = (const float*)d_in[14];
    const float* gs1  = (const float*)d_in[15];
    const float* gs2  = (const float*)d_in[16];
    const float* gv1  = (const float*)d_in[17];
    const float* gv2  = (const float*)d_in[18];

    float* ws  = (float*)d_ws;
    float* out = (float*)d_out;

    hipLaunchKernelGGL(mask_norm_kernel, dim3(8), dim3(256), 0, stream,
                       mask_raw, (unsigned char*)(ws + OFF_MSK));
    hipLaunchKernelGGL(transpose_kernel, dim3(1280), dim3(256), 0, stream,
                       Wq, Wk, gs1, gv1, Wre, gs2, gv2, Wrs, ws);
    hipLaunchKernelGGL(node_kernel, dim3(BB*NN/4), dim3(256), 0, stream,
                       h, ln_w, ln_b, ws);
    hipLaunchKernelGGL(attn_kernel, dim3(BB*NN), dim3(256), 0, stream,
                       t_ij, nbr, ws);
    hipLaunchKernelGGL((combine_kernel<0>), dim3(BB*NN), dim3(256), 0, stream,
                       t_ij, r_ij, nbr, r1, r2, X1, X2, ws, out);
    hipLaunchKernelGGL((combine_kernel<1>), dim3(BB*NN), dim3(256), 0, stream,
                       t_ij, r_ij, nbr, r1, r2, X1, X2, ws, out);
    hipLaunchKernelGGL((combine_kernel<2>), dim3(BB*NN), dim3(256), 0, stream,
                       t_ij, r_ij, nbr, r1, r2, X1, X2, ws, out);
}

// Round 7
// 782.577 us; speedup vs baseline: 2.1263x; 1.0365x over previous
//
#include <hip/hip_runtime.h>

#define BB 2
#define NN 512
#define JJ 32
#define DD 256
#define HH 8
#define MM 5
#define MD 1280

// workspace layout (float offsets)
#define OFF_WQ   0          // 256x256 transposed
#define OFF_WK   65536
#define OFF_GS1  131072
#define OFF_GV1  196608
#define OFF_WRE  262144
#define OFF_GS2  327680     // 256x1280 transposed
#define OFF_GV2  655360
#define OFF_WRS  983040
#define OFF_Q    1310720    // B*N*D
#define OFF_K    1572864
#define OFF_X    1835008    // B*N*MD
#define OFF_V    3145728
#define OFF_MSK  4456448    // normalized mask bytes (8192 floats)
#define OFF_ATTN 4464640    // attn weights [1024][32][8], pre-scaled by norm
// total 4726784 floats = 18.9 MB

__device__ __forceinline__ float silu_f(float x){ return x / (1.0f + expf(-x)); }

// ---------------- mask normalization (8 blocks; per-block layout detect) ----------------
__global__ void mask_norm_kernel(const unsigned int* __restrict__ raw,
                                 unsigned char* __restrict__ outm) {
    __shared__ int flag_s;
    const int tid = threadIdx.x;
    const int blk = blockIdx.x;              // 8 blocks
    if (tid == 0) flag_s = 0;
    __syncthreads();
    int bad = 0;
    for (int i = tid; i < 1024; i += 256) bad |= (raw[blk*1024 + i] > 1u) ? 1 : 0;
    if (bad) atomicOr(&flag_s, 1);
    __syncthreads();
    const int base = blk * 4096;             // byte-index region
    if (flag_s) {   // byte layout
        const unsigned char* rb = (const unsigned char*)raw;
        for (int i = tid; i < 4096; i += 256) outm[base + i] = rb[base + i] ? 1 : 0;
    } else {        // int32 layout
        for (int i = tid; i < 4096; i += 256) outm[base + i] = raw[base + i] ? 1 : 0;
    }
}

// ---------------- LDS-tiled weight transpose (coalesced both sides) ----------------
__global__ __launch_bounds__(256) void transpose_kernel(
        const float* __restrict__ Wq, const float* __restrict__ Wk,
        const float* __restrict__ gs1, const float* __restrict__ gv1,
        const float* __restrict__ Wre, const float* __restrict__ gs2,
        const float* __restrict__ gv2, const float* __restrict__ Wrs,
        float* __restrict__ ws) {
    __shared__ float tile[32][33];
    const int bid = blockIdx.x;              // 1280 tiles
    const float* src; float* dst; int R, tr, tc;
    if (bid < 320) {                          // 5 square matrices, 64 tiles each
        int m = bid >> 6, t = bid & 63;
        tr = t >> 3; tc = t & 7; R = 256;
        src = (m==0)?Wq:(m==1)?Wk:(m==2)?gs1:(m==3)?gv1:Wre;
        dst = ws + m*65536;
    } else {                                  // 3 big (1280x256), 320 tiles each
        int b2 = bid - 320;
        int m = b2 / 320, t = b2 % 320;
        tr = t >> 3; tc = t & 7; R = 1280;
        src = (m==0)?gs2:(m==1)?gv2:Wrs;
        dst = ws + OFF_GS2 + m*327680;
    }
    const int r = threadIdx.x >> 5, c = threadIdx.x & 31;
    #pragma unroll
    for (int s = 0; s < 4; s++)
        tile[r + 8*s][c] = src[(size_t)(tr*32 + r + 8*s)*256 + tc*32 + c];
    __syncthreads();
    #pragma unroll
    for (int s = 0; s < 4; s++)
        dst[(size_t)(tc*32 + r + 8*s)*R + tr*32 + c] = tile[c][r + 8*s];
}

// ---------------- node kernel: LN + q,k + gated MLPs (4 rows/block) ----------------
__global__ __launch_bounds__(256) void node_kernel(const float* __restrict__ h,
                                                   const float* __restrict__ ln_w,
                                                   const float* __restrict__ ln_b,
                                                   float* __restrict__ ws) {
    __shared__ float hs[4][256];
    __shared__ float s1s[4][256];
    __shared__ float v1s[4][256];
    __shared__ float mu_s[4], rstd_s[4];
    const int tid = threadIdx.x;
    const int row0 = blockIdx.x * 4;

    #pragma unroll
    for (int r = 0; r < 4; r++) hs[r][tid] = h[(size_t)(row0 + r)*256 + tid];
    __syncthreads();

    {   // layernorm: 64-lane group g reduces row g
        int g = tid >> 6, l = tid & 63;
        float s = 0.f;
        #pragma unroll
        for (int k = 0; k < 4; k++) s += hs[g][l + 64*k];
        #pragma unroll
        for (int off = 32; off > 0; off >>= 1) s += __shfl_xor(s, off, 64);
        float mu = s * (1.0f/256.0f);
        float v = 0.f;
        #pragma unroll
        for (int k = 0; k < 4; k++) { float d0 = hs[g][l + 64*k] - mu; v += d0*d0; }
        #pragma unroll
        for (int off = 32; off > 0; off >>= 1) v += __shfl_xor(v, off, 64);
        if (l == 0) { mu_s[g] = mu; rstd_s[g] = rsqrtf(v*(1.0f/256.0f) + 1e-5f); }
    }
    __syncthreads();
    {
        float w = ln_w[tid], bb = ln_b[tid];
        #pragma unroll
        for (int r = 0; r < 4; r++) hs[r][tid] = (hs[r][tid] - mu_s[r]) * rstd_s[r] * w + bb;
    }
    __syncthreads();

    {   // stage 1
        float aq[4], ak[4], a1[4], a2[4];
        #pragma unroll
        for (int r = 0; r < 4; r++) { aq[r]=0.f; ak[r]=0.f; a1[r]=0.f; a2[r]=0.f; }
        const float* WqT  = ws + OFF_WQ;
        const float* WkT  = ws + OFF_WK;
        const float* G1T  = ws + OFF_GS1;
        const float* Gv1T = ws + OFF_GV1;
        for (int e = 0; e < 256; e++) {
            float wq = WqT[e*256 + tid];
            float wk = WkT[e*256 + tid];
            float w1 = G1T[e*256 + tid];
            float w2 = Gv1T[e*256 + tid];
            #pragma unroll
            for (int r = 0; r < 4; r++) {
                float hv = hs[r][e];
                aq[r] += hv*wq; ak[r] += hv*wk; a1[r] += hv*w1; a2[r] += hv*w2;
            }
        }
        #pragma unroll
        for (int r = 0; r < 4; r++) {
            ws[OFF_Q + (size_t)(row0 + r)*256 + tid] = aq[r];
            ws[OFF_K + (size_t)(row0 + r)*256 + tid] = ak[r];
            s1s[r][tid] = silu_f(a1[r]);
            v1s[r][tid] = silu_f(a2[r]);
        }
    }
    __syncthreads();

    {   // stage 2
        float ax[4][5], av[4][5];
        #pragma unroll
        for (int r = 0; r < 4; r++)
            #pragma unroll
            for (int m = 0; m < 5; m++) { ax[r][m]=0.f; av[r][m]=0.f; }
        const float* G2T  = ws + OFF_GS2;
        const float* Gv2T = ws + OFF_GV2;
        for (int e = 0; e < 256; e++) {
            float wx[5], wv[5];
            #pragma unroll
            for (int m = 0; m < 5; m++) {
                wx[m] = G2T [e*1280 + m*256 + tid];
                wv[m] = Gv2T[e*1280 + m*256 + tid];
            }
            #pragma unroll
            for (int r = 0; r < 4; r++) {
                float s1v = s1s[r][e], v1v = v1s[r][e];
                #pragma unroll
                for (int m = 0; m < 5; m++) { ax[r][m] += s1v*wx[m]; av[r][m] += v1v*wv[m]; }
            }
        }
        #pragma unroll
        for (int r = 0; r < 4; r++)
            #pragma unroll
            for (int m = 0; m < 5; m++) {
                ws[OFF_X + (size_t)(row0 + r)*1280 + m*256 + tid] = ax[r][m];
                ws[OFF_V + (size_t)(row0 + r)*1280 + m*256 + tid] = av[r][m];
            }
    }
}

// ---------------- attn kernel: phases A+B, writes pre-scaled weights ----------------
__global__ __launch_bounds__(256) void attn_kernel(const float* __restrict__ t_ij,
                                                   const int* __restrict__ nbr,
                                                   float* __restrict__ ws) {
    __shared__ float t_s[JJ][DD];     // 32 KB
    __shared__ float q_s[DD];
    __shared__ float attn_s[JJ][HH];
    __shared__ int   nbr_s[JJ];
    __shared__ int   msk_s[JJ];
    __shared__ float norm_s;

    const int tid = threadIdx.x;
    const int bi  = blockIdx.x;
    const int b   = bi >> 9;
    const unsigned char* mask = (const unsigned char*)(ws + OFF_MSK);

    if (tid < JJ) {
        nbr_s[tid] = nbr[bi*JJ + tid];
        msk_s[tid] = mask[bi*JJ + tid] ? 1 : 0;
    }
    q_s[tid] = ws[OFF_Q + (size_t)bi*256 + tid];
    for (int j = 0; j < JJ; j++)
        t_s[j][tid] = t_ij[((size_t)bi*JJ + j)*256 + tid];
    __syncthreads();
    if (tid == 0) {
        int n = 0;
        for (int j = 0; j < JJ; j++) n += msk_s[j];
        norm_s = sqrtf((float)n) * (1.0f/16.0f);
    }

    // t_attn column tid for all 32 j
    float ta[JJ];
    #pragma unroll
    for (int j = 0; j < JJ; j++) ta[j] = 0.f;
    {
        const float* WreT = ws + OFF_WRE;
        for (int e = 0; e < 256; e += 4) {
            float w4[4];
            #pragma unroll
            for (int s = 0; s < 4; s++) w4[s] = WreT[(e+s)*256 + tid];
            #pragma unroll
            for (int j = 0; j < JJ; j++) {
                const float4 tv = *reinterpret_cast<const float4*>(&t_s[j][e]);
                ta[j] += tv.x*w4[0] + tv.y*w4[1] + tv.z*w4[2] + tv.w*w4[3];
            }
        }
    }
    {
        float qv = q_s[tid];
        #pragma unroll
        for (int j = 0; j < JJ; j++) {
            float kv = ws[OFF_K + (size_t)(b*NN + nbr_s[j])*256 + tid];
            float p = qv * kv * silu_f(ta[j]);
            #pragma unroll
            for (int off = 16; off > 0; off >>= 1) p += __shfl_xor(p, off, 32);
            if ((tid & 31) == 0) attn_s[j][tid >> 5] = p;
        }
    }
    __syncthreads();
    {   // masked softmax + scale, write to ws
        int hh = tid >> 5, j = tid & 31;
        float l = msk_s[j] ? attn_s[j][hh] : -1e9f;
        float mx = l;
        #pragma unroll
        for (int off = 16; off > 0; off >>= 1) mx = fmaxf(mx, __shfl_xor(mx, off, 32));
        float e0 = expf(l - mx);
        float ssum = e0;
        #pragma unroll
        for (int off = 16; off > 0; off >>= 1) ssum += __shfl_xor(ssum, off, 32);
        ws[OFF_ATTN + (size_t)bi*256 + j*8 + hh] = (e0 / ssum) * norm_s;
    }
}

// ---------------- merged combine kernel: all 5 m-slices, j-tiles of 8 ----------------
// Round-6 evidence: 3 separate combines each paid the full t_s LDS sweep and
// staged t_ij 3x; VGPR=60 with 64 live accums => AGPR shuttling (3x VALU per
// FMA). Fix: one kernel, tf[8][5]=40 accums (fits arch VGPRs), 20 FMA per
// ds_read_b128. Rule #20: every tf/acc index is compile-time (jj, m, c all
// unrolled); only LDS arrays use runtime j.
__global__ __launch_bounds__(256, 4) void combine_all_kernel(
        const float* __restrict__ t_ij, const float* __restrict__ r_ij,
        const int* __restrict__ nbr,
        const float* __restrict__ r1, const float* __restrict__ r2,
        const float* __restrict__ X1, const float* __restrict__ X2,
        const float* __restrict__ ws, float* __restrict__ out) {
    __shared__ float t_s[JJ][DD];     // 32 KB
    __shared__ float attn_l[JJ][HH];
    __shared__ float cut_s[JJ];
    __shared__ float r1_s[JJ][3];
    __shared__ float r2_s[JJ][5];
    __shared__ int   nbr_s[JJ];

    const int tid = threadIdx.x;
    const int bi  = blockIdx.x;
    const int b   = bi >> 9;

    if (tid < JJ) {
        int eidx = bi*JJ + tid;
        nbr_s[tid] = nbr[eidx];
        float r = r_ij[eidx];
        cut_s[tid] = (r < 5.0f) ? 0.5f*(cosf(r * 0.62831853071795864f) + 1.0f) : 0.0f;
        #pragma unroll
        for (int c = 0; c < 3; c++) r1_s[tid][c] = r1[eidx*3 + c];
        #pragma unroll
        for (int c = 0; c < 5; c++) r2_s[tid][c] = r2[eidx*5 + c];
    }
    attn_l[tid >> 3][tid & 7] = ws[OFF_ATTN + (size_t)bi*256 + tid];
    for (int j = 0; j < JJ; j++)
        t_s[j][tid] = t_ij[((size_t)bi*JJ + j)*256 + tid];
    __syncthreads();

    // head of flat index m*256+tid (dh_group = 160 = M*D/H per head)
    int hm[5];
    #pragma unroll
    for (int m = 0; m < 5; m++) hm[m] = (m*256 + tid) / 160;

    const float* WrsT = ws + OFF_WRS;
    const float* Xb = ws + OFF_X + (size_t)b*NN*1280;
    const float* Vb = ws + OFF_V + (size_t)b*NN*1280;

    float acc_dh = 0.f;
    float acc1[3] = {0.f, 0.f, 0.f};
    float acc2[5] = {0.f, 0.f, 0.f, 0.f, 0.f};

    for (int p = 0; p < 4; p++) {              // j-tiles of 8 (NOT unrolled)
        const int j0 = p * 8;
        float tf[8][5];
        #pragma unroll
        for (int jj = 0; jj < 8; jj++)
            #pragma unroll
            for (int m = 0; m < 5; m++) tf[jj][m] = 0.f;

        for (int e = 0; e < 256; e += 4) {
            float w[4][5];                     // [s][m]
            #pragma unroll
            for (int s = 0; s < 4; s++)
                #pragma unroll
                for (int m = 0; m < 5; m++)
                    w[s][m] = WrsT[(size_t)(e+s)*1280 + m*256 + tid];
            #pragma unroll
            for (int jj = 0; jj < 8; jj++) {
                const float4 tv = *reinterpret_cast<const float4*>(&t_s[j0 + jj][e]);
                #pragma unroll
                for (int m = 0; m < 5; m++)
                    tf[jj][m] += tv.x*w[0][m] + tv.y*w[1][m] + tv.z*w[2][m] + tv.w*w[3][m];
            }
        }

        #pragma unroll
        for (int jj = 0; jj < 8; jj++) {
            const int j = j0 + jj;
            const int nb = nbr_s[j];
            const float cut = cut_s[j];
            const float* xr  = Xb + (size_t)nb*1280;
            const float* vr  = Vb + (size_t)nb*1280;
            const float* x1r = X1 + ((size_t)(b*NN + nb))*768;
            const float* x2r = X2 + ((size_t)(b*NN + nb))*1280;

            float o0 = tf[jj][0]*xr[0*256 + tid]*cut + attn_l[j][hm[0]]*vr[0*256 + tid];
            float o1 = tf[jj][1]*xr[1*256 + tid]*cut + attn_l[j][hm[1]]*vr[1*256 + tid];
            float o2 = tf[jj][2]*xr[2*256 + tid]*cut + attn_l[j][hm[2]]*vr[2*256 + tid];
            float o3 = tf[jj][3]*xr[3*256 + tid]*cut + attn_l[j][hm[3]]*vr[3*256 + tid];
            float o4 = tf[jj][4]*xr[4*256 + tid]*cut + attn_l[j][hm[4]]*vr[4*256 + tid];

            acc_dh += o0;
            #pragma unroll
            for (int c = 0; c < 3; c++)
                acc1[c] += r1_s[j][c]*o1 + x1r[c*256 + tid]*o3;
            #pragma unroll
            for (int c = 0; c < 5; c++)
                acc2[c] += r2_s[j][c]*o2 + x2r[c*256 + tid]*o4;
        }
    }

    // outputs: d_h | dX1 | dX2 concatenated
    out[(size_t)bi*256 + tid] = acc_dh;
    #pragma unroll
    for (int c = 0; c < 3; c++)
        out[262144 + ((size_t)bi*3 + c)*256 + tid] = acc1[c];
    #pragma unroll
    for (int c = 0; c < 5; c++)
        out[1048576 + ((size_t)bi*5 + c)*256 + tid] = acc2[c];
}

extern "C" void kernel_launch(void* const* d_in, const int* in_sizes, int n_in,
                              void* d_out, int out_size, void* d_ws, size_t ws_size,
                              hipStream_t stream) {
    const float* h    = (const float*)d_in[0];
    const float* X1   = (const float*)d_in[1];
    const float* X2   = (const float*)d_in[2];
    const float* r1   = (const float*)d_in[3];
    const float* r2   = (const float*)d_in[4];
    const float* t_ij = (const float*)d_in[5];
    const float* r_ij = (const float*)d_in[6];
    const int*   nbr  = (const int*)d_in[7];
    const unsigned int* mask_raw = (const unsigned int*)d_in[8];
    const float* ln_w = (const float*)d_in[9];
    const float* ln_b = (const float*)d_in[10];
    const float* Wq   = (const float*)d_in[11];
    const float* Wk   = (const float*)d_in[12];
    const float* Wre  = (const float*)d_in[13];
    const float* Wrs  = (const float*)d_in[14];
    const float* gs1  = (const float*)d_in[15];
    const float* gs2  = (const float*)d_in[16];
    const float* gv1  = (const float*)d_in[17];
    const float* gv2  = (const float*)d_in[18];

    float* ws  = (float*)d_ws;
    float* out = (float*)d_out;

    hipLaunchKernelGGL(mask_norm_kernel, dim3(8), dim3(256), 0, stream,
                       mask_raw, (unsigned char*)(ws + OFF_MSK));
    hipLaunchKernelGGL(transpose_kernel, dim3(1280), dim3(256), 0, stream,
                       Wq, Wk, gs1, gv1, Wre, gs2, gv2, Wrs, ws);
    hipLaunchKernelGGL(node_kernel, dim3(BB*NN/4), dim3(256), 0, stream,
                       h, ln_w, ln_b, ws);
    hipLaunchKernelGGL(attn_kernel, dim3(BB*NN), dim3(256), 0, stream,
                       t_ij, nbr, ws);
    hipLaunchKernelGGL(combine_all_kernel, dim3(BB*NN), dim3(256), 0, stream,
                       t_ij, r_ij, nbr, r1, r2, X1, X2, ws, out);
}

// Round 8
// 740.396 us; speedup vs baseline: 2.2474x; 1.0570x over previous
//
#include <hip/hip_runtime.h>

#define BB 2
#define NN 512
#define JJ 32
#define DD 256
#define HH 8
#define MM 5
#define MD 1280

// workspace layout (float offsets)
#define OFF_WQ   0          // 256x256 transposed
#define OFF_WK   65536
#define OFF_GS1  131072
#define OFF_GV1  196608
#define OFF_WRE  262144
#define OFF_GS2  327680     // 256x1280 transposed
#define OFF_GV2  655360
#define OFF_WRS  983040
#define OFF_Q    1310720    // B*N*D
#define OFF_K    1572864
#define OFF_X    1835008    // B*N*MD
#define OFF_V    3145728
#define OFF_MSK  4456448    // normalized mask bytes (8192 floats)
#define OFF_ATTN 4464640    // attn weights [1024][32][8], pre-scaled by norm
// total 4726784 floats = 18.9 MB

__device__ __forceinline__ float silu_f(float x){ return x / (1.0f + expf(-x)); }

// ---------------- mask normalization (8 blocks; per-block layout detect) ----------------
__global__ void mask_norm_kernel(const unsigned int* __restrict__ raw,
                                 unsigned char* __restrict__ outm) {
    __shared__ int flag_s;
    const int tid = threadIdx.x;
    const int blk = blockIdx.x;              // 8 blocks
    if (tid == 0) flag_s = 0;
    __syncthreads();
    int bad = 0;
    for (int i = tid; i < 1024; i += 256) bad |= (raw[blk*1024 + i] > 1u) ? 1 : 0;
    if (bad) atomicOr(&flag_s, 1);
    __syncthreads();
    const int base = blk * 4096;             // byte-index region
    if (flag_s) {   // byte layout
        const unsigned char* rb = (const unsigned char*)raw;
        for (int i = tid; i < 4096; i += 256) outm[base + i] = rb[base + i] ? 1 : 0;
    } else {        // int32 layout
        for (int i = tid; i < 4096; i += 256) outm[base + i] = raw[base + i] ? 1 : 0;
    }
}

// ---------------- LDS-tiled weight transpose (coalesced both sides) ----------------
__global__ __launch_bounds__(256) void transpose_kernel(
        const float* __restrict__ Wq, const float* __restrict__ Wk,
        const float* __restrict__ gs1, const float* __restrict__ gv1,
        const float* __restrict__ Wre, const float* __restrict__ gs2,
        const float* __restrict__ gv2, const float* __restrict__ Wrs,
        float* __restrict__ ws) {
    __shared__ float tile[32][33];
    const int bid = blockIdx.x;              // 1280 tiles
    const float* src; float* dst; int R, tr, tc;
    if (bid < 320) {                          // 5 square matrices, 64 tiles each
        int m = bid >> 6, t = bid & 63;
        tr = t >> 3; tc = t & 7; R = 256;
        src = (m==0)?Wq:(m==1)?Wk:(m==2)?gs1:(m==3)?gv1:Wre;
        dst = ws + m*65536;
    } else {                                  // 3 big (1280x256), 320 tiles each
        int b2 = bid - 320;
        int m = b2 / 320, t = b2 % 320;
        tr = t >> 3; tc = t & 7; R = 1280;
        src = (m==0)?gs2:(m==1)?gv2:Wrs;
        dst = ws + OFF_GS2 + m*327680;
    }
    const int r = threadIdx.x >> 5, c = threadIdx.x & 31;
    #pragma unroll
    for (int s = 0; s < 4; s++)
        tile[r + 8*s][c] = src[(size_t)(tr*32 + r + 8*s)*256 + tc*32 + c];
    __syncthreads();
    #pragma unroll
    for (int s = 0; s < 4; s++)
        dst[(size_t)(tc*32 + r + 8*s)*R + tr*32 + c] = tile[c][r + 8*s];
}

// ---------------- node kernel: LN + q,k + gated MLPs (4 rows/block) ----------------
__global__ __launch_bounds__(256) void node_kernel(const float* __restrict__ h,
                                                   const float* __restrict__ ln_w,
                                                   const float* __restrict__ ln_b,
                                                   float* __restrict__ ws) {
    __shared__ float hs[4][256];
    __shared__ float s1s[4][256];
    __shared__ float v1s[4][256];
    __shared__ float mu_s[4], rstd_s[4];
    const int tid = threadIdx.x;
    const int row0 = blockIdx.x * 4;

    #pragma unroll
    for (int r = 0; r < 4; r++) hs[r][tid] = h[(size_t)(row0 + r)*256 + tid];
    __syncthreads();

    {   // layernorm: 64-lane group g reduces row g
        int g = tid >> 6, l = tid & 63;
        float s = 0.f;
        #pragma unroll
        for (int k = 0; k < 4; k++) s += hs[g][l + 64*k];
        #pragma unroll
        for (int off = 32; off > 0; off >>= 1) s += __shfl_xor(s, off, 64);
        float mu = s * (1.0f/256.0f);
        float v = 0.f;
        #pragma unroll
        for (int k = 0; k < 4; k++) { float d0 = hs[g][l + 64*k] - mu; v += d0*d0; }
        #pragma unroll
        for (int off = 32; off > 0; off >>= 1) v += __shfl_xor(v, off, 64);
        if (l == 0) { mu_s[g] = mu; rstd_s[g] = rsqrtf(v*(1.0f/256.0f) + 1e-5f); }
    }
    __syncthreads();
    {
        float w = ln_w[tid], bb = ln_b[tid];
        #pragma unroll
        for (int r = 0; r < 4; r++) hs[r][tid] = (hs[r][tid] - mu_s[r]) * rstd_s[r] * w + bb;
    }
    __syncthreads();

    {   // stage 1
        float aq[4], ak[4], a1[4], a2[4];
        #pragma unroll
        for (int r = 0; r < 4; r++) { aq[r]=0.f; ak[r]=0.f; a1[r]=0.f; a2[r]=0.f; }
        const float* WqT  = ws + OFF_WQ;
        const float* WkT  = ws + OFF_WK;
        const float* G1T  = ws + OFF_GS1;
        const float* Gv1T = ws + OFF_GV1;
        for (int e = 0; e < 256; e++) {
            float wq = WqT[e*256 + tid];
            float wk = WkT[e*256 + tid];
            float w1 = G1T[e*256 + tid];
            float w2 = Gv1T[e*256 + tid];
            #pragma unroll
            for (int r = 0; r < 4; r++) {
                float hv = hs[r][e];
                aq[r] += hv*wq; ak[r] += hv*wk; a1[r] += hv*w1; a2[r] += hv*w2;
            }
        }
        #pragma unroll
        for (int r = 0; r < 4; r++) {
            ws[OFF_Q + (size_t)(row0 + r)*256 + tid] = aq[r];
            ws[OFF_K + (size_t)(row0 + r)*256 + tid] = ak[r];
            s1s[r][tid] = silu_f(a1[r]);
            v1s[r][tid] = silu_f(a2[r]);
        }
    }
    __syncthreads();

    {   // stage 2
        float ax[4][5], av[4][5];
        #pragma unroll
        for (int r = 0; r < 4; r++)
            #pragma unroll
            for (int m = 0; m < 5; m++) { ax[r][m]=0.f; av[r][m]=0.f; }
        const float* G2T  = ws + OFF_GS2;
        const float* Gv2T = ws + OFF_GV2;
        for (int e = 0; e < 256; e++) {
            float wx[5], wv[5];
            #pragma unroll
            for (int m = 0; m < 5; m++) {
                wx[m] = G2T [e*1280 + m*256 + tid];
                wv[m] = Gv2T[e*1280 + m*256 + tid];
            }
            #pragma unroll
            for (int r = 0; r < 4; r++) {
                float s1v = s1s[r][e], v1v = v1s[r][e];
                #pragma unroll
                for (int m = 0; m < 5; m++) { ax[r][m] += s1v*wx[m]; av[r][m] += v1v*wv[m]; }
            }
        }
        #pragma unroll
        for (int r = 0; r < 4; r++)
            #pragma unroll
            for (int m = 0; m < 5; m++) {
                ws[OFF_X + (size_t)(row0 + r)*1280 + m*256 + tid] = ax[r][m];
                ws[OFF_V + (size_t)(row0 + r)*1280 + m*256 + tid] = av[r][m];
            }
    }
}

// ---------------- attn kernel: phases A+B, writes pre-scaled weights ----------------
__global__ __launch_bounds__(256) void attn_kernel(const float* __restrict__ t_ij,
                                                   const int* __restrict__ nbr,
                                                   float* __restrict__ ws) {
    __shared__ float t_s[JJ][DD];     // 32 KB
    __shared__ float q_s[DD];
    __shared__ float attn_s[JJ][HH];
    __shared__ int   nbr_s[JJ];
    __shared__ int   msk_s[JJ];
    __shared__ float norm_s;

    const int tid = threadIdx.x;
    const int bi  = blockIdx.x;
    const int b   = bi >> 9;
    const unsigned char* mask = (const unsigned char*)(ws + OFF_MSK);

    if (tid < JJ) {
        nbr_s[tid] = nbr[bi*JJ + tid];
        msk_s[tid] = mask[bi*JJ + tid] ? 1 : 0;
    }
    q_s[tid] = ws[OFF_Q + (size_t)bi*256 + tid];
    for (int j = 0; j < JJ; j++)
        t_s[j][tid] = t_ij[((size_t)bi*JJ + j)*256 + tid];
    __syncthreads();
    if (tid == 0) {
        int n = 0;
        for (int j = 0; j < JJ; j++) n += msk_s[j];
        norm_s = sqrtf((float)n) * (1.0f/16.0f);
    }

    // t_attn column tid for all 32 j
    float ta[JJ];
    #pragma unroll
    for (int j = 0; j < JJ; j++) ta[j] = 0.f;
    {
        const float* WreT = ws + OFF_WRE;
        for (int e = 0; e < 256; e += 4) {
            float w4[4];
            #pragma unroll
            for (int s = 0; s < 4; s++) w4[s] = WreT[(e+s)*256 + tid];
            #pragma unroll
            for (int j = 0; j < JJ; j++) {
                const float4 tv = *reinterpret_cast<const float4*>(&t_s[j][e]);
                ta[j] += tv.x*w4[0] + tv.y*w4[1] + tv.z*w4[2] + tv.w*w4[3];
            }
        }
    }
    {
        float qv = q_s[tid];
        #pragma unroll
        for (int j = 0; j < JJ; j++) {
            float kv = ws[OFF_K + (size_t)(b*NN + nbr_s[j])*256 + tid];
            float p = qv * kv * silu_f(ta[j]);
            #pragma unroll
            for (int off = 16; off > 0; off >>= 1) p += __shfl_xor(p, off, 32);
            if ((tid & 31) == 0) attn_s[j][tid >> 5] = p;
        }
    }
    __syncthreads();
    {   // masked softmax + scale, write to ws
        int hh = tid >> 5, j = tid & 31;
        float l = msk_s[j] ? attn_s[j][hh] : -1e9f;
        float mx = l;
        #pragma unroll
        for (int off = 16; off > 0; off >>= 1) mx = fmaxf(mx, __shfl_xor(mx, off, 32));
        float e0 = expf(l - mx);
        float ssum = e0;
        #pragma unroll
        for (int off = 16; off > 0; off >>= 1) ssum += __shfl_xor(ssum, off, 32);
        ws[OFF_ATTN + (size_t)bi*256 + j*8 + hh] = (e0 / ssum) * norm_s;
    }
}

// ---------------- merged combine kernel: all 5 m-slices, j-tiles of 8 ----------------
// Round-7 evidence: __launch_bounds__(256,4) capped the unified reg budget at
// 128; compiler kept 64 arch VGPRs and parked tf[8][5] in AGPRs, paying
// v_accvgpr_read/write around every FMA (measured: VALUBusy 73% with FMA only
// 28% of cycles => ~2 extra VALU ops per FMA). Fix: (256,2) -> 256-reg budget
// so tf lives in arch VGPRs. Occupancy 2 blocks/CU is fine: the kernel is
// instruction-count-bound with 40 independent accumulator chains.
__global__ __launch_bounds__(256, 2) void combine_all_kernel(
        const float* __restrict__ t_ij, const float* __restrict__ r_ij,
        const int* __restrict__ nbr,
        const float* __restrict__ r1, const float* __restrict__ r2,
        const float* __restrict__ X1, const float* __restrict__ X2,
        const float* __restrict__ ws, float* __restrict__ out) {
    __shared__ float t_s[JJ][DD];     // 32 KB
    __shared__ float attn_l[JJ][HH];
    __shared__ float cut_s[JJ];
    __shared__ float r1_s[JJ][3];
    __shared__ float r2_s[JJ][5];
    __shared__ int   nbr_s[JJ];

    const int tid = threadIdx.x;
    const int bi  = blockIdx.x;
    const int b   = bi >> 9;

    if (tid < JJ) {
        int eidx = bi*JJ + tid;
        nbr_s[tid] = nbr[eidx];
        float r = r_ij[eidx];
        cut_s[tid] = (r < 5.0f) ? 0.5f*(cosf(r * 0.62831853071795864f) + 1.0f) : 0.0f;
        #pragma unroll
        for (int c = 0; c < 3; c++) r1_s[tid][c] = r1[eidx*3 + c];
        #pragma unroll
        for (int c = 0; c < 5; c++) r2_s[tid][c] = r2[eidx*5 + c];
    }
    attn_l[tid >> 3][tid & 7] = ws[OFF_ATTN + (size_t)bi*256 + tid];
    for (int j = 0; j < JJ; j++)
        t_s[j][tid] = t_ij[((size_t)bi*JJ + j)*256 + tid];
    __syncthreads();

    // head of flat index m*256+tid (dh_group = 160 = M*D/H per head)
    int hm[5];
    #pragma unroll
    for (int m = 0; m < 5; m++) hm[m] = (m*256 + tid) / 160;

    const float* WrsT = ws + OFF_WRS;
    const float* Xb = ws + OFF_X + (size_t)b*NN*1280;
    const float* Vb = ws + OFF_V + (size_t)b*NN*1280;

    float acc_dh = 0.f;
    float acc1[3] = {0.f, 0.f, 0.f};
    float acc2[5] = {0.f, 0.f, 0.f, 0.f, 0.f};

    for (int p = 0; p < 4; p++) {              // j-tiles of 8 (NOT unrolled)
        const int j0 = p * 8;
        float tf[8][5];
        #pragma unroll
        for (int jj = 0; jj < 8; jj++)
            #pragma unroll
            for (int m = 0; m < 5; m++) tf[jj][m] = 0.f;

        for (int e = 0; e < 256; e += 4) {
            float w[4][5];                     // [s][m]
            #pragma unroll
            for (int s = 0; s < 4; s++)
                #pragma unroll
                for (int m = 0; m < 5; m++)
                    w[s][m] = WrsT[(size_t)(e+s)*1280 + m*256 + tid];
            #pragma unroll
            for (int jj = 0; jj < 8; jj++) {
                const float4 tv = *reinterpret_cast<const float4*>(&t_s[j0 + jj][e]);
                #pragma unroll
                for (int m = 0; m < 5; m++)
                    tf[jj][m] += tv.x*w[0][m] + tv.y*w[1][m] + tv.z*w[2][m] + tv.w*w[3][m];
            }
        }

        #pragma unroll
        for (int jj = 0; jj < 8; jj++) {
            const int j = j0 + jj;
            const int nb = nbr_s[j];
            const float cut = cut_s[j];
            const float* xr  = Xb + (size_t)nb*1280;
            const float* vr  = Vb + (size_t)nb*1280;
            const float* x1r = X1 + ((size_t)(b*NN + nb))*768;
            const float* x2r = X2 + ((size_t)(b*NN + nb))*1280;

            float o0 = tf[jj][0]*xr[0*256 + tid]*cut + attn_l[j][hm[0]]*vr[0*256 + tid];
            float o1 = tf[jj][1]*xr[1*256 + tid]*cut + attn_l[j][hm[1]]*vr[1*256 + tid];
            float o2 = tf[jj][2]*xr[2*256 + tid]*cut + attn_l[j][hm[2]]*vr[2*256 + tid];
            float o3 = tf[jj][3]*xr[3*256 + tid]*cut + attn_l[j][hm[3]]*vr[3*256 + tid];
            float o4 = tf[jj][4]*xr[4*256 + tid]*cut + attn_l[j][hm[4]]*vr[4*256 + tid];

            acc_dh += o0;
            #pragma unroll
            for (int c = 0; c < 3; c++)
                acc1[c] += r1_s[j][c]*o1 + x1r[c*256 + tid]*o3;
            #pragma unroll
            for (int c = 0; c < 5; c++)
                acc2[c] += r2_s[j][c]*o2 + x2r[c*256 + tid]*o4;
        }
    }

    // outputs: d_h | dX1 | dX2 concatenated
    out[(size_t)bi*256 + tid] = acc_dh;
    #pragma unroll
    for (int c = 0; c < 3; c++)
        out[262144 + ((size_t)bi*3 + c)*256 + tid] = acc1[c];
    #pragma unroll
    for (int c = 0; c < 5; c++)
        out[1048576 + ((size_t)bi*5 + c)*256 + tid] = acc2[c];
}

extern "C" void kernel_launch(void* const* d_in, const int* in_sizes, int n_in,
                              void* d_out, int out_size, void* d_ws, size_t ws_size,
                              hipStream_t stream) {
    const float* h    = (const float*)d_in[0];
    const float* X1   = (const float*)d_in[1];
    const float* X2   = (const float*)d_in[2];
    const float* r1   = (const float*)d_in[3];
    const float* r2   = (const float*)d_in[4];
    const float* t_ij = (const float*)d_in[5];
    const float* r_ij = (const float*)d_in[6];
    const int*   nbr  = (const int*)d_in[7];
    const unsigned int* mask_raw = (const unsigned int*)d_in[8];
    const float* ln_w = (const float*)d_in[9];
    const float* ln_b = (const float*)d_in[10];
    const float* Wq   = (const float*)d_in[11];
    const float* Wk   = (const float*)d_in[12];
    const float* Wre  = (const float*)d_in[13];
    const float* Wrs  = (const float*)d_in[14];
    const float* gs1  = (const float*)d_in[15];
    const float* gs2  = (const float*)d_in[16];
    const float* gv1  = (const float*)d_in[17];
    const float* gv2  = (const float*)d_in[18];

    float* ws  = (float*)d_ws;
    float* out = (float*)d_out;

    hipLaunchKernelGGL(mask_norm_kernel, dim3(8), dim3(256), 0, stream,
                       mask_raw, (unsigned char*)(ws + OFF_MSK));
    hipLaunchKernelGGL(transpose_kernel, dim3(1280), dim3(256), 0, stream,
                       Wq, Wk, gs1, gv1, Wre, gs2, gv2, Wrs, ws);
    hipLaunchKernelGGL(node_kernel, dim3(BB*NN/4), dim3(256), 0, stream,
                       h, ln_w, ln_b, ws);
    hipLaunchKernelGGL(attn_kernel, dim3(BB*NN), dim3(256), 0, stream,
                       t_ij, nbr, ws);
    hipLaunchKernelGGL(combine_all_kernel, dim3(BB*NN), dim3(256), 0, stream,
                       t_ij, r_ij, nbr, r1, r2, X1, X2, ws, out);
}